// Round 6
// baseline (395.928 us; speedup 1.0000x reference)
//
#include <hip/hip_runtime.h>
#include <math.h>

#define NSRC 50000
#define NDST 50000
#define NE   500000
#define HD   128
#define EDIM 32
#define LN_EPS 1e-5f

typedef __attribute__((ext_vector_type(8))) short short8;   // 8 bf16 = 4 VGPR
typedef __attribute__((ext_vector_type(4))) float f32x4;
typedef unsigned short u16;

__device__ __forceinline__ float fast_tanh(float x) {
    float e = __expf(2.f * x);
    return 1.f - 2.f / (e + 1.f);
}
__device__ __forceinline__ u16 f2b(float x) {           // f32 -> bf16 RNE
    unsigned u = __float_as_uint(x);
    return (u16)((u + 0x7FFFu + ((u >> 16) & 1u)) >> 16);
}
__device__ __forceinline__ float b2f(u16 h) {
    return __uint_as_float(((unsigned)h) << 16);
}
__device__ __forceinline__ short8 ld8(const u16* p) { return *(const short8*)p; }

// ---------------------------------------------------------------------------
// fold_small: WeMsg = We@Wmsg (32x128), c2 = be@Wmsg, bsm = bsrc@Wmsg + bmsg
// 34 blocks x 128 threads.
// ---------------------------------------------------------------------------
__global__ __launch_bounds__(128) void fold_small_kernel(
    const float* __restrict__ We,   const float* __restrict__ be,
    const float* __restrict__ Wsrc, const float* __restrict__ bsrc,
    const float* __restrict__ Wmsg, const float* __restrict__ bmsg,
    float* __restrict__ WeMsg, float* __restrict__ c2, float* __restrict__ bsm)
{
    const int j = threadIdx.x;
    const int b = blockIdx.x;
    float s = 0.f;
    if (b < 32) {
        for (int k = 0; k < 128; ++k) s += We[b*HD + k] * Wmsg[k*HD + j];
        WeMsg[b*HD + j] = s;
    } else if (b == 32) {
        for (int k = 0; k < 128; ++k) s += be[k] * Wmsg[k*HD + j];
        c2[j] = s;
    } else {
        for (int k = 0; k < 128; ++k) s += bsrc[k] * Wmsg[k*HD + j];
        bsm[j] = s + bmsg[j];
    }
}

// ---------------------------------------------------------------------------
// fold_pack: produce all bf16 MFMA-B-fragment packed weights + bias2.
// Pack layout: dst[(lb*64 + lane)*8 + j] = bf16(src[(kc*32+quad*8+j)*128 + t*16+ln])
//   lb = local block 0..31 (K=128) or 0..7 (K=32), kc=lb>>3, t=lb&7,
//   ln=lane&15, quad=lane>>4.
// blocks: 0-31 Wsrc, 32-63 Wdst, 64-95 Wsm=Wsrc@Wmsg (inline), 96-127 Wout1+I,
//         128-159 Wout2, 160-167 We, 168-175 W3=WeMsg@Wout2 (inline),
//         176: bias2 = bout + c2@Wout2. 64 threads/block.
// ---------------------------------------------------------------------------
__global__ __launch_bounds__(64) void fold_pack_kernel(
    const float* __restrict__ Wsrc, const float* __restrict__ Wdst,
    const float* __restrict__ Wmsg, const float* __restrict__ Wout,
    const float* __restrict__ We,   const float* __restrict__ WeMsg,
    const float* __restrict__ c2,   const float* __restrict__ bout,
    u16* __restrict__ Wsrc_pk, u16* __restrict__ Wdst_pk,
    u16* __restrict__ Wsm_pk,  u16* __restrict__ W1_pk,
    u16* __restrict__ W2_pk,   u16* __restrict__ We_pk,
    u16* __restrict__ W3_pk,   float* __restrict__ bias2)
{
    const int b = blockIdx.x;
    const int lane = threadIdx.x;
    const float* Wout2 = Wout + HD*HD;

    if (b == 176) {
        for (int h = 0; h < 2; ++h) {
            int j = lane + h*64;
            float s = 0.f;
            for (int k = 0; k < 128; ++k) s += c2[k] * Wout2[k*HD + j];
            bias2[j] = s + bout[j];
        }
        return;
    }

    int lb, mode; const float* src; u16* dst;
    if      (b < 32)  { lb = b;       mode = 0; src = Wsrc;  dst = Wsrc_pk; }
    else if (b < 64)  { lb = b - 32;  mode = 0; src = Wdst;  dst = Wdst_pk; }
    else if (b < 96)  { lb = b - 64;  mode = 1; src = Wsrc;  dst = Wsm_pk;  } // @Wmsg
    else if (b < 128) { lb = b - 96;  mode = 2; src = Wout;  dst = W1_pk;   } // +I
    else if (b < 160) { lb = b - 128; mode = 0; src = Wout2; dst = W2_pk;   }
    else if (b < 168) { lb = b - 160; mode = 0; src = We;    dst = We_pk;   }
    else              { lb = b - 168; mode = 3; src = WeMsg; dst = W3_pk;   } // @Wout2

    const int kc = lb >> 3, t = lb & 7;
    const int ln = lane & 15, quad = lane >> 4;
    const int col = t*16 + ln;
    u16 tmp[8];
#pragma unroll
    for (int j = 0; j < 8; ++j) {
        const int row = kc*32 + quad*8 + j;
        float v;
        if (mode == 0) {
            v = src[row*HD + col];
        } else if (mode == 2) {
            v = src[row*HD + col] + ((row == col) ? 1.f : 0.f);
        } else if (mode == 1) {
            float s = 0.f;
            for (int k = 0; k < 128; ++k) s += src[row*HD + k] * Wmsg[k*HD + col];
            v = s;
        } else {
            float s = 0.f;
            for (int k = 0; k < 128; ++k) s += src[row*HD + k] * Wout2[k*HD + col];
            v = s;
        }
        tmp[j] = f2b(v);
    }
    *(short8*)(dst + (size_t)(lb*64 + lane)*8) = *(short8*)tmp;
}

// ---------------------------------------------------------------------------
// convert_ea + hist: ea f32 -> bf16 (4 elems/thread), and dst-degree histogram.
// ---------------------------------------------------------------------------
__global__ __launch_bounds__(256) void convert_ea_kernel(
    const float* __restrict__ ea, const int* __restrict__ ei,
    u16* __restrict__ eab, int* __restrict__ cnt)
{
    int i = blockIdx.x * 256 + threadIdx.x;
    if (i < NE) atomicAdd(&cnt[ei[NE + i]], 1);
    if (i < NE*EDIM/4) {
        float4 v = ((const float4*)ea)[i];
        u16 o[4] = { f2b(v.x), f2b(v.y), f2b(v.z), f2b(v.w) };
        *(ushort4*)(eab + (size_t)i*4) = *(ushort4*)o;
    }
}

// ---------------------------------------------------------------------------
// node_gemm: per 16 src rows (1 wave): s1 = tanhdot(sx@Wsrc+bsrc, wa1) and
// srcmsgb = bf16(sx@Wsm + bsm). Reads f32 src_x directly (converts to A-frags).
// ---------------------------------------------------------------------------
__global__ __launch_bounds__(256) void node_gemm_kernel(
    const float* __restrict__ sx, const u16* __restrict__ Wsrc_pk,
    const u16* __restrict__ Wsm_pk, const float* __restrict__ bsrc,
    const float* __restrict__ bsm, const float* __restrict__ wa1,
    float* __restrict__ s1, u16* __restrict__ srcmsgb)
{
    __shared__ u16 lds[4 * 16 * HD];     // 16 KB, one 16x128 slab per wave
    const int t = threadIdx.x;
    const int w = t >> 6, lane = t & 63;
    const int ln = lane & 15, quad = lane >> 4;
    int row0 = (blockIdx.x * 4 + w) * 16;
    if (row0 > NSRC - 16) row0 = NSRC - 16;      // clamp (dup writes benign)

    const float4* sx4 = (const float4*)sx;
    short8 a[4];
#pragma unroll
    for (int kc = 0; kc < 4; ++kc) {
        float4 p0 = sx4[(size_t)(row0 + ln)*32 + kc*8 + quad*2];
        float4 p1 = sx4[(size_t)(row0 + ln)*32 + kc*8 + quad*2 + 1];
        u16 tmp[8] = { f2b(p0.x), f2b(p0.y), f2b(p0.z), f2b(p0.w),
                       f2b(p1.x), f2b(p1.y), f2b(p1.z), f2b(p1.w) };
        a[kc] = *(short8*)tmp;
    }

    // ---- s1 path
    float v[4] = {0.f, 0.f, 0.f, 0.f};
#pragma unroll
    for (int tt = 0; tt < 8; ++tt) {
        f32x4 acc = {0.f, 0.f, 0.f, 0.f};
#pragma unroll
        for (int kc = 0; kc < 4; ++kc) {
            short8 b = ld8(Wsrc_pk + (size_t)((kc*8 + tt)*64 + lane)*8);
            acc = __builtin_amdgcn_mfma_f32_16x16x32_bf16(a[kc], b, acc, 0, 0, 0);
        }
        const float bb = bsrc[tt*16 + ln];
        const float ww = wa1[tt*16 + ln];
#pragma unroll
        for (int r = 0; r < 4; ++r) v[r] += fast_tanh(acc[r] + bb) * ww;
    }
#pragma unroll
    for (int off = 8; off >= 1; off >>= 1)
#pragma unroll
        for (int r = 0; r < 4; ++r) v[r] += __shfl_xor(v[r], off);
    if (ln == 0) {
#pragma unroll
        for (int r = 0; r < 4; ++r) s1[row0 + quad*4 + r] = v[r];
    }

    // ---- srcmsg path
#pragma unroll
    for (int tt = 0; tt < 8; ++tt) {
        f32x4 acc = {0.f, 0.f, 0.f, 0.f};
#pragma unroll
        for (int kc = 0; kc < 4; ++kc) {
            short8 b = ld8(Wsm_pk + (size_t)((kc*8 + tt)*64 + lane)*8);
            acc = __builtin_amdgcn_mfma_f32_16x16x32_bf16(a[kc], b, acc, 0, 0, 0);
        }
        const float bb = bsm[tt*16 + ln];
#pragma unroll
        for (int r = 0; r < 4; ++r)
            lds[w*2048 + (quad*4 + r)*HD + tt*16 + ln] = f2b(acc[r] + bb);
    }
    __syncthreads();
#pragma unroll
    for (int r = 0; r < 4; ++r) {
        int idx = r*512 + lane*8;
        short8 val = *(short8*)(lds + w*2048 + idx);
        int row = idx >> 7, col = idx & 127;
        *(short8*)(srcmsgb + (size_t)(row0 + row)*HD + col) = val;
    }
}

// ---------------------------------------------------------------------------
// dst_gemm: s2 = tanhdot(dx@Wdst+bdst, wa2); also emits dxb = bf16(dx)
// ---------------------------------------------------------------------------
__global__ __launch_bounds__(256) void dst_gemm_kernel(
    const float* __restrict__ dx, const u16* __restrict__ Wdst_pk,
    const float* __restrict__ bdst, const float* __restrict__ wa2,
    float* __restrict__ s2, u16* __restrict__ dxb)
{
    const int t = threadIdx.x;
    const int w = t >> 6, lane = t & 63;
    const int ln = lane & 15, quad = lane >> 4;
    int row0 = (blockIdx.x * 4 + w) * 16;
    if (row0 > NDST - 16) row0 = NDST - 16;

    const float4* dx4 = (const float4*)dx;
    short8 a[4];
#pragma unroll
    for (int kc = 0; kc < 4; ++kc) {
        float4 p0 = dx4[(size_t)(row0 + ln)*32 + kc*8 + quad*2];
        float4 p1 = dx4[(size_t)(row0 + ln)*32 + kc*8 + quad*2 + 1];
        u16 tmp[8] = { f2b(p0.x), f2b(p0.y), f2b(p0.z), f2b(p0.w),
                       f2b(p1.x), f2b(p1.y), f2b(p1.z), f2b(p1.w) };
        a[kc] = *(short8*)tmp;
        *(short8*)(dxb + (size_t)(row0 + ln)*HD + kc*32 + quad*8) = a[kc];
    }

    float v[4] = {0.f, 0.f, 0.f, 0.f};
#pragma unroll
    for (int tt = 0; tt < 8; ++tt) {
        f32x4 acc = {0.f, 0.f, 0.f, 0.f};
#pragma unroll
        for (int kc = 0; kc < 4; ++kc) {
            short8 b = ld8(Wdst_pk + (size_t)((kc*8 + tt)*64 + lane)*8);
            acc = __builtin_amdgcn_mfma_f32_16x16x32_bf16(a[kc], b, acc, 0, 0, 0);
        }
        const float bb = bdst[tt*16 + ln];
        const float ww = wa2[tt*16 + ln];
#pragma unroll
        for (int r = 0; r < 4; ++r) v[r] += fast_tanh(acc[r] + bb) * ww;
    }
#pragma unroll
    for (int off = 8; off >= 1; off >>= 1)
#pragma unroll
        for (int r = 0; r < 4; ++r) v[r] += __shfl_xor(v[r], off);
    if (ln == 0) {
#pragma unroll
        for (int r = 0; r < 4; ++r) s2[row0 + quad*4 + r] = v[r];
    }
}

// ---------------------------------------------------------------------------
// CSR scan (wave-shuffle version, 2 barriers)
// ---------------------------------------------------------------------------
__global__ __launch_bounds__(1024) void scan1_kernel(
    const int* __restrict__ cnt, int* __restrict__ excl, int* __restrict__ bsum)
{
    __shared__ int wsum[16];
    const int t = threadIdx.x;
    const int lane = t & 63, wv = t >> 6;
    const int i = blockIdx.x * 1024 + t;
    int v = (i < NDST) ? cnt[i] : 0;
    int x = v;
#pragma unroll
    for (int off = 1; off < 64; off <<= 1) {
        int u = __shfl_up(x, off);
        if (lane >= off) x += u;
    }
    if (lane == 63) wsum[wv] = x;
    __syncthreads();
    if (t < 16) {
        int s = wsum[t];
#pragma unroll
        for (int off = 1; off < 16; off <<= 1) {
            int u = __shfl_up(s, off);
            if (t >= off) s += u;
        }
        wsum[t] = s;
    }
    __syncthreads();
    int prefix = (wv > 0) ? wsum[wv - 1] : 0;
    int incl = prefix + x;
    if (i < NDST) excl[i] = incl - v;
    if (t == 1023) bsum[blockIdx.x] = incl;
}

__global__ void scan2_kernel(int* __restrict__ bsum, int* __restrict__ rowptr)
{
    const int NB = (NDST + 1023) / 1024;
    const int t = threadIdx.x;
    int orig = (t < NB) ? bsum[t] : 0;
    int v = orig;
    for (int off = 1; off < 64; off <<= 1) {
        int u = __shfl_up(v, off);
        if (t >= off) v += u;
    }
    int total = __shfl(v, 63);
    if (t < NB) bsum[t] = v - orig;
    if (t == 0) rowptr[NDST] = total;
}

__global__ void scan3_kernel(const int* __restrict__ bsum,
                             int* __restrict__ rowptr, int* __restrict__ cursor)
{
    int i = blockIdx.x * 256 + threadIdx.x;
    if (i < NDST) {
        int v = rowptr[i] + bsum[i >> 10];
        rowptr[i] = v;
        cursor[i] = v;
    }
}

// ---------------------------------------------------------------------------
// scatter + s12: ev[pos] = (src, e); s12[e] = s1[src] + s2[dst] + battn
// ---------------------------------------------------------------------------
__global__ void scatter_kernel(const int* __restrict__ ei,
                               int* __restrict__ cursor,
                               const float* __restrict__ s1,
                               const float* __restrict__ s2,
                               const float* __restrict__ battn,
                               int2* __restrict__ ev, float* __restrict__ s12)
{
    int e = blockIdx.x * 256 + threadIdx.x;
    if (e < NE) {
        int src = ei[e], dst = ei[NE + e];
        int pos = atomicAdd(&cursor[dst], 1);
        ev[pos] = make_int2(src, e);
        s12[e] = s1[src] + s2[dst] + battn[0];
    }
}

// ---------------------------------------------------------------------------
// edge_score: 32 edges / wave (2 A-frags share each B-load).
// score[e] = tanhdot(ea@We+be, wa3) + s12[e], written sequentially.
// NOTE: s12 is read via plain loads INSIDE the divergent writer branch —
// no cross-lane shfl under divergence (that was R5's correctness bug).
// ---------------------------------------------------------------------------
__global__ __launch_bounds__(256) void edge_score_kernel(
    const u16* __restrict__ eab, const u16* __restrict__ We_pk,
    const float* __restrict__ be, const float* __restrict__ wattn,
    const float* __restrict__ s12, float* __restrict__ scores)
{
    const int t = threadIdx.x;
    const int w = t >> 6, lane = t & 63;
    const int ln = lane & 15, quad = lane >> 4;
    const int e0 = (blockIdx.x * 4 + w) * 32;
    if (e0 >= NE) return;                  // NE%32==0, no partial tiles

    short8 a0 = ld8(eab + (size_t)(e0 + ln)*EDIM + quad*8);
    short8 a1 = ld8(eab + (size_t)(e0 + 16 + ln)*EDIM + quad*8);
    const float* wa3 = wattn + 2*HD;

    float v0[4] = {0.f, 0.f, 0.f, 0.f};
    float v1[4] = {0.f, 0.f, 0.f, 0.f};
#pragma unroll
    for (int tt = 0; tt < 8; ++tt) {
        short8 b = ld8(We_pk + (size_t)(tt*64 + lane)*8);
        f32x4 acc0 = {0.f, 0.f, 0.f, 0.f};
        f32x4 acc1 = {0.f, 0.f, 0.f, 0.f};
        acc0 = __builtin_amdgcn_mfma_f32_16x16x32_bf16(a0, b, acc0, 0, 0, 0);
        acc1 = __builtin_amdgcn_mfma_f32_16x16x32_bf16(a1, b, acc1, 0, 0, 0);
        const float bb = be[tt*16 + ln];
        const float ww = wa3[tt*16 + ln];
#pragma unroll
        for (int r = 0; r < 4; ++r) {
            v0[r] += fast_tanh(acc0[r] + bb) * ww;
            v1[r] += fast_tanh(acc1[r] + bb) * ww;
        }
    }
#pragma unroll
    for (int off = 8; off >= 1; off >>= 1)
#pragma unroll
        for (int r = 0; r < 4; ++r) {
            v0[r] += __shfl_xor(v0[r], off);
            v1[r] += __shfl_xor(v1[r], off);
        }

    if (ln == 0) {
#pragma unroll
        for (int r = 0; r < 4; ++r) {
            int j0 = quad*4 + r;
            int j1 = j0 + 16;
            scores[e0 + j0] = v0[r] + s12[e0 + j0];
            scores[e0 + j1] = v1[r] + s12[e0 + j1];
        }
    }
}

// ---------------------------------------------------------------------------
// dst_agg: 1 wave per dst. scores gathered via ev[i].y (2MB, L2-resident);
// 4 edges in flight; 16 lanes x 16B per bf16 srcmsg row.
// Outputs aggSb (bf16 [NDST,128]), weab (bf16 [NDST,32]). Empty: aggSb=-c2.
// ---------------------------------------------------------------------------
__global__ __launch_bounds__(256) void dst_agg_kernel(
    const int2* __restrict__ ev, const int* __restrict__ rowptr,
    const float* __restrict__ scores, const u16* __restrict__ srcmsgb,
    const u16* __restrict__ eab, const float* __restrict__ c2,
    u16* __restrict__ aggSb, u16* __restrict__ weab)
{
    const int lane = threadIdx.x & 63;
    const int d = blockIdx.x * 4 + (threadIdx.x >> 6);
    const int el = lane >> 4, c = lane & 15;
    const int start = rowptr[d], end = rowptr[d + 1];

    if (start == end) {
        if (el == 0) {
            u16 z[8];
#pragma unroll
            for (int j = 0; j < 8; ++j) z[j] = f2b(-c2[c*8 + j]);
            *(short8*)(aggSb + (size_t)d*HD + c*8) = *(short8*)z;
            if (c < 4) {
                u16 zz[8] = {0,0,0,0,0,0,0,0};
                *(short8*)(weab + (size_t)d*EDIM + c*8) = *(short8*)zz;
            }
        }
        return;
    }

    float m = -3.4e38f;
    for (int i = start + lane; i < end; i += 64)
        m = fmaxf(m, scores[ev[i].y]);
#pragma unroll
    for (int off = 32; off; off >>= 1) m = fmaxf(m, __shfl_xor(m, off));

    float s = 0.f;
    for (int i = start + lane; i < end; i += 64)
        s += __expf(scores[ev[i].y] - m);
#pragma unroll
    for (int off = 32; off; off >>= 1) s += __shfl_xor(s, off);
    const float inv = 1.f / s;

    float acc[8] = {0,0,0,0,0,0,0,0};
    float wacc[8] = {0,0,0,0,0,0,0,0};
    for (int i0 = start; i0 < end; i0 += 4) {
        int i = i0 + el;
        bool val = (i < end);
        int ii = val ? i : start;
        int2 se = ev[ii];
        float w = val ? __expf(scores[se.y] - m) : 0.f;
        short8 sm = ld8(srcmsgb + (size_t)se.x*HD + c*8);
#pragma unroll
        for (int j = 0; j < 8; ++j) acc[j] += w * b2f(((u16*)&sm)[j]);
        if (c < 4) {
            short8 eav = ld8(eab + (size_t)se.y*EDIM + c*8);
#pragma unroll
            for (int j = 0; j < 8; ++j) wacc[j] += w * b2f(((u16*)&eav)[j]);
        }
    }
#pragma unroll
    for (int off = 16; off <= 32; off <<= 1) {
#pragma unroll
        for (int j = 0; j < 8; ++j) {
            acc[j]  += __shfl_xor(acc[j],  off);
            wacc[j] += __shfl_xor(wacc[j], off);
        }
    }
    if (el == 0) {
        u16 o[8];
#pragma unroll
        for (int j = 0; j < 8; ++j) o[j] = f2b(acc[j] * inv);
        *(short8*)(aggSb + (size_t)d*HD + c*8) = *(short8*)o;
        if (c < 4) {
            u16 o2[8];
#pragma unroll
            for (int j = 0; j < 8; ++j) o2[j] = f2b(wacc[j] * inv);
            *(short8*)(weab + (size_t)d*EDIM + c*8) = *(short8*)o2;
        }
    }
}

// ---------------------------------------------------------------------------
// final: out = LN(dxb@W1p + aggSb@Wout2 + weab@W3 + bias2) * gamma + beta
// ---------------------------------------------------------------------------
__global__ __launch_bounds__(256) void final_kernel(
    const u16* __restrict__ dxb, const u16* __restrict__ aggSb,
    const u16* __restrict__ weab,
    const u16* __restrict__ W1_pk, const u16* __restrict__ W2_pk,
    const u16* __restrict__ W3_pk, const float* __restrict__ bias2,
    const float* __restrict__ gamma, const float* __restrict__ beta,
    float* __restrict__ out)
{
    const int t = threadIdx.x;
    const int w = t >> 6, lane = t & 63;
    const int ln = lane & 15, quad = lane >> 4;
    int row0 = (blockIdx.x * 4 + w) * 16;
    if (row0 > NDST - 16) row0 = NDST - 16;

    short8 a1[4], a2[4], a3;
#pragma unroll
    for (int kc = 0; kc < 4; ++kc) {
        a1[kc] = ld8(dxb   + (size_t)(row0 + ln)*HD + kc*32 + quad*8);
        a2[kc] = ld8(aggSb + (size_t)(row0 + ln)*HD + kc*32 + quad*8);
    }
    a3 = ld8(weab + (size_t)(row0 + ln)*EDIM + quad*8);

    f32x4 accs[8];
#pragma unroll
    for (int tt = 0; tt < 8; ++tt) {
        f32x4 acc = {0.f, 0.f, 0.f, 0.f};
#pragma unroll
        for (int kc = 0; kc < 4; ++kc) {
            short8 b = ld8(W1_pk + (size_t)((kc*8 + tt)*64 + lane)*8);
            acc = __builtin_amdgcn_mfma_f32_16x16x32_bf16(a1[kc], b, acc, 0, 0, 0);
        }
#pragma unroll
        for (int kc = 0; kc < 4; ++kc) {
            short8 b = ld8(W2_pk + (size_t)((kc*8 + tt)*64 + lane)*8);
            acc = __builtin_amdgcn_mfma_f32_16x16x32_bf16(a2[kc], b, acc, 0, 0, 0);
        }
        {
            short8 b = ld8(W3_pk + (size_t)(tt*64 + lane)*8);
            acc = __builtin_amdgcn_mfma_f32_16x16x32_bf16(a3, b, acc, 0, 0, 0);
        }
        const float bb = bias2[tt*16 + ln];
#pragma unroll
        for (int r = 0; r < 4; ++r) acc[r] += bb;
        accs[tt] = acc;
    }

    const float gl[8] = { gamma[ln], gamma[16+ln], gamma[32+ln], gamma[48+ln],
                          gamma[64+ln], gamma[80+ln], gamma[96+ln], gamma[112+ln] };
    const float bl[8] = { beta[ln], beta[16+ln], beta[32+ln], beta[48+ln],
                          beta[64+ln], beta[80+ln], beta[96+ln], beta[112+ln] };
#pragma unroll
    for (int r = 0; r < 4; ++r) {
        float s = 0.f, q = 0.f;
#pragma unroll
        for (int tt = 0; tt < 8; ++tt) {
            float u = accs[tt][r];
            s += u; q += u*u;
        }
#pragma unroll
        for (int off = 8; off >= 1; off >>= 1) {
            s += __shfl_xor(s, off);
            q += __shfl_xor(q, off);
        }
        const float mean = s * (1.f / HD);
        const float var  = q * (1.f / HD) - mean * mean;
        const float rstd = rsqrtf(var + LN_EPS);
        const int row = row0 + quad*4 + r;
#pragma unroll
        for (int tt = 0; tt < 8; ++tt)
            out[(size_t)row*HD + tt*16 + ln] =
                (accs[tt][r] - mean) * rstd * gl[tt] + bl[tt];
    }
}

// ---------------------------------------------------------------------------
extern "C" void kernel_launch(void* const* d_in, const int* in_sizes, int n_in,
                              void* d_out, int out_size, void* d_ws, size_t ws_size,
                              hipStream_t stream)
{
    const float* src_x = (const float*)d_in[0];
    const float* dst_x = (const float*)d_in[1];
    const int*   ei    = (const int*)d_in[2];
    const float* eattr = (const float*)d_in[3];
    const float* Wsrc  = (const float*)d_in[4];
    const float* bsrc  = (const float*)d_in[5];
    const float* Wdst  = (const float*)d_in[6];
    const float* bdst  = (const float*)d_in[7];
    const float* We    = (const float*)d_in[8];
    const float* be    = (const float*)d_in[9];
    const float* Wattn = (const float*)d_in[10];
    const float* battn = (const float*)d_in[11];
    const float* Wmsg  = (const float*)d_in[12];
    const float* bmsg  = (const float*)d_in[13];
    const float* Wout  = (const float*)d_in[14];
    const float* bout  = (const float*)d_in[15];
    const float* gamma = (const float*)d_in[16];
    const float* beta  = (const float*)d_in[17];
    float* out = (float*)d_out;

    float* ws = (float*)d_ws;
    u16* dxb     = (u16*)(ws + 0);            // 6.4M bf16
    u16* eab     = (u16*)(ws + 3200000);      // 16M bf16
    u16* srcmsgb = (u16*)(ws + 11200000);     // 6.4M bf16
    u16* aggSb   = (u16*)(ws + 14400000);     // 6.4M bf16
    u16* weab    = (u16*)(ws + 17600000);     // 1.6M bf16
    float* s1    = ws + 18400000;             // 50048
    float* s2    = ws + 18450048;             // 50048
    float* scores= ws + 18500096;             // 500000
    float* s12   = ws + 19000096;             // 500000
    float* WeMsg = ws + 19500096;             // 4096
    float* c2    = ws + 19504192;             // 128
    float* bsm   = ws + 19504320;             // 128
    float* bias2 = ws + 19504448;             // 128
    u16* Wsrc_pk = (u16*)(ws + 19504576);     // 16384 u16
    u16* Wdst_pk = (u16*)(ws + 19512768);
    u16* Wsm_pk  = (u16*)(ws + 19520960);
    u16* W1_pk   = (u16*)(ws + 19529152);
    u16* W2_pk   = (u16*)(ws + 19537344);
    u16* We_pk   = (u16*)(ws + 19545536);     // 4096 u16
    u16* W3_pk   = (u16*)(ws + 19547584);
    int* rowptr  = (int*)(ws + 19549632);     // 50016
    int* cursor  = rowptr + 50016;
    int2* ev     = (int2*)(cursor + 50016);   // 500000 int2
    int* bsum    = (int*)ev + 1000000;        // 64

    hipMemsetAsync(cursor, 0, NDST * sizeof(int), stream);

    fold_small_kernel<<<34, 128, 0, stream>>>(We, be, Wsrc, bsrc, Wmsg, bmsg,
                                              WeMsg, c2, bsm);
    fold_pack_kernel<<<177, 64, 0, stream>>>(Wsrc, Wdst, Wmsg, Wout, We, WeMsg,
                                             c2, bout,
                                             Wsrc_pk, Wdst_pk, Wsm_pk, W1_pk,
                                             W2_pk, We_pk, W3_pk, bias2);
    convert_ea_kernel<<<15625, 256, 0, stream>>>(eattr, ei, eab, cursor);

    const int g16 = (NSRC/16 + 3) / 4;        // 782 blocks, 4 waves each

    node_gemm_kernel<<<g16, 256, 0, stream>>>(src_x, Wsrc_pk, Wsm_pk, bsrc, bsm,
                                              Wattn, s1, srcmsgb);
    dst_gemm_kernel<<<g16, 256, 0, stream>>>(dst_x, Wdst_pk, bdst, Wattn + HD,
                                             s2, dxb);

    scan1_kernel<<<(NDST + 1023) / 1024, 1024, 0, stream>>>(cursor, rowptr, bsum);
    scan2_kernel<<<1, 64, 0, stream>>>(bsum, rowptr);
    scan3_kernel<<<(NDST + 255) / 256, 256, 0, stream>>>(bsum, rowptr, cursor);
    scatter_kernel<<<(NE + 255) / 256, 256, 0, stream>>>(ei, cursor, s1, s2,
                                                         battn, ev, s12);

    edge_score_kernel<<<(NE/32 + 3) / 4, 256, 0, stream>>>(
        eab, We_pk, be, Wattn, s12, scores);

    dst_agg_kernel<<<NDST / 4, 256, 0, stream>>>(ev, rowptr, scores, srcmsgb,
                                                 eab, c2, aggSb, weab);

    final_kernel<<<g16, 256, 0, stream>>>(dxb, aggSb, weab, W1_pk, W2_pk, W3_pk,
                                          bias2, gamma, beta, out);
}